// Round 1
// baseline (296.653 us; speedup 1.0000x reference)
//
#include <hip/hip_runtime.h>
#include <hip/hip_bf16.h>

typedef __attribute__((ext_vector_type(8))) short bf16x8;
typedef __attribute__((ext_vector_type(4))) float f32x4;

#define MFMA16x16x32(a, b, c) __builtin_amdgcn_mfma_f32_16x16x32_bf16(a, b, c, 0, 0, 0)

__device__ __forceinline__ unsigned short f2b(float x) {
    union { float f; unsigned int u; } v; v.f = x;
    unsigned int r = v.u + 0x7FFFu + ((v.u >> 16) & 1u);
    return (unsigned short)(r >> 16);
}

// ---------------- fp32 -> bf16 convert (hidden states) ----------------
__global__ __launch_bounds__(256) void cvt_bf16_kernel(const float* __restrict__ in,
                                                       unsigned short* __restrict__ out, int n) {
    int i = (blockIdx.x * 256 + threadIdx.x) * 4;
    if (i >= n) return;
    float4 v = *reinterpret_cast<const float4*>(in + i);
    ushort4 o;
    o.x = f2b(v.x); o.y = f2b(v.y); o.z = f2b(v.z); o.w = f2b(v.w);
    *reinterpret_cast<ushort4*>(out + i) = o;
}

// ---------------- W [K][N] fp32 -> WT [N][K] bf16 (tiled transpose) ----------------
__global__ __launch_bounds__(256) void transpose_cvt_kernel(const float* __restrict__ Wq,
                                                            const float* __restrict__ Wk,
                                                            const float* __restrict__ Wv,
                                                            unsigned short* __restrict__ WTall) {
    int z = blockIdx.z;
    const float* in = (z == 0) ? Wq : (z == 1) ? Wk : Wv;
    unsigned short* outp = WTall + (size_t)z * 1024 * 1024;
    __shared__ float tile[32][33];
    int tx = threadIdx.x, ty = threadIdx.y;
    int x = blockIdx.x * 32 + tx;       // n
    int y0 = blockIdx.y * 32;           // k base
    #pragma unroll
    for (int j = ty; j < 32; j += 8)
        tile[j][tx] = in[(size_t)(y0 + j) * 1024 + x];
    __syncthreads();
    int ox = y0 + tx;                   // k
    int oy0 = blockIdx.x * 32;          // n base
    #pragma unroll
    for (int j = ty; j < 32; j += 8)
        outp[(size_t)(oy0 + j) * 1024 + ox] = f2b(tile[tx][j]);
}

// ---------------- T5 relative bias table: bt[h][n] for n = max(q-k,0) ----------------
__global__ __launch_bounds__(256) void build_bt_kernel(const float* __restrict__ rel_bias,
                                                       float* __restrict__ bt) {
    int n = blockIdx.x * 256 + threadIdx.x;
    if (n >= 2048) return;
    int bucket;
    if (n < 16) {
        bucket = n;
    } else {
        float nf = (float)n;
        int v = 16 + (int)((logf(nf / 16.0f) / 0.69314718f) * 16.0f);
        bucket = v < 31 ? v : 31;
    }
    #pragma unroll
    for (int h = 0; h < 16; ++h)
        bt[(size_t)h * 2048 + n] = rel_bias[bucket * 16 + h];
}

// ---------------- QKV projection GEMM: C = A(bf16) * W + bias -> bf16 ----------------
// A: [4096][1024] bf16 row-major; WT: [N=1024][K=1024] bf16 (transposed W); C: [4096][1024] bf16
// 128x128 tile, 4 waves (2x2), each wave 64x64 = 4x4 fragments of 16x16, BK=32.
__global__ __launch_bounds__(256) void gemm_qkv_kernel(const unsigned short* __restrict__ A,
                                                       const unsigned short* __restrict__ WTall,
                                                       const float* __restrict__ bq,
                                                       const float* __restrict__ bk,
                                                       const float* __restrict__ bv,
                                                       unsigned short* __restrict__ qkv) {
    const int K = 1024, N = 1024;
    int z = blockIdx.z;
    const unsigned short* B = WTall + (size_t)z * 1024 * 1024;
    const float* bias = (z == 0) ? bq : (z == 1) ? bk : bv;
    unsigned short* C = qkv + (size_t)z * 4096 * 1024;

    __shared__ unsigned short As[128][40];  // 32 cols + 8 pad (2-way bank conflict = free)
    __shared__ unsigned short Bs[128][40];

    int t = threadIdx.x;
    int lane = t & 63, w = t >> 6;
    int wr = w >> 1, wc = w & 1;
    int g = lane >> 4, r = lane & 15;
    int m0 = blockIdx.x * 128, n0 = blockIdx.y * 128;

    int lr = t >> 2, lc = (t & 3) * 8;      // staging: 2 rows x 8 cols per thread per matrix

    f32x4 acc[4][4] = {};

    for (int kb = 0; kb < K; kb += 32) {
        bf16x8 a0 = *reinterpret_cast<const bf16x8*>(A + (size_t)(m0 + lr) * K + kb + lc);
        bf16x8 a1 = *reinterpret_cast<const bf16x8*>(A + (size_t)(m0 + 64 + lr) * K + kb + lc);
        bf16x8 b0 = *reinterpret_cast<const bf16x8*>(B + (size_t)(n0 + lr) * K + kb + lc);
        bf16x8 b1 = *reinterpret_cast<const bf16x8*>(B + (size_t)(n0 + 64 + lr) * K + kb + lc);
        __syncthreads();
        *reinterpret_cast<bf16x8*>(&As[lr][lc]) = a0;
        *reinterpret_cast<bf16x8*>(&As[64 + lr][lc]) = a1;
        *reinterpret_cast<bf16x8*>(&Bs[lr][lc]) = b0;
        *reinterpret_cast<bf16x8*>(&Bs[64 + lr][lc]) = b1;
        __syncthreads();

        bf16x8 af[4], bfr[4];
        #pragma unroll
        for (int i = 0; i < 4; ++i)
            af[i] = *reinterpret_cast<const bf16x8*>(&As[wr * 64 + i * 16 + r][g * 8]);
        #pragma unroll
        for (int j = 0; j < 4; ++j)
            bfr[j] = *reinterpret_cast<const bf16x8*>(&Bs[wc * 64 + j * 16 + r][g * 8]);
        #pragma unroll
        for (int i = 0; i < 4; ++i) {
            #pragma unroll
            for (int j = 0; j < 4; ++j)
                acc[i][j] = MFMA16x16x32(af[i], bfr[j], acc[i][j]);
        }
    }

    #pragma unroll
    for (int j = 0; j < 4; ++j) {
        int n = n0 + wc * 64 + j * 16 + r;
        float bj = bias[n];
        #pragma unroll
        for (int i = 0; i < 4; ++i) {
            int mbase = m0 + wr * 64 + i * 16 + g * 4;
            #pragma unroll
            for (int e = 0; e < 4; ++e)
                C[(size_t)(mbase + e) * N + n] = f2b(acc[i][j][e] + bj);
        }
    }
}

// ---------------- Flash attention with T5 bias ----------------
// Grid: (qtile=32, bh=32). Block 256 = 4 waves; each wave owns 16 q-rows.
// KBLK=32 keys/iter; swapped QK^T (mfma(K,Q)) so lane's softmax state is q = lane&15.
__global__ __launch_bounds__(256) void attn_kernel(const unsigned short* __restrict__ qkv,
                                                   const float* __restrict__ bt,
                                                   float* __restrict__ out) {
    const int S = 2048;
    int bh = blockIdx.y;
    int b = bh >> 4, h = bh & 15;
    int qt = blockIdx.x;
    int t = threadIdx.x;
    int lane = t & 63, w = t >> 6;
    int g = lane >> 4, r = lane & 15;

    const unsigned short* qg = qkv;
    const unsigned short* kg = qkv + (size_t)4096 * 1024;
    const unsigned short* vg = qkv + (size_t)2 * 4096 * 1024;

    __shared__ unsigned short Ks[32][72];       // [key][dh] +8 pad
    __shared__ unsigned short Vs[64][40];       // [dh][key] transposed, +8 pad
    __shared__ unsigned short Ps[4][16][40];    // per-wave P tile [q][key], +8 pad
    __shared__ float bts[2048];                 // bias LUT for this head

    for (int i = t; i < 2048; i += 256) bts[i] = bt[(size_t)h * 2048 + i];

    int qrow = qt * 64 + w * 16 + r;            // this lane's q row (softmax state owner)
    const unsigned short* qptr = qg + ((size_t)(b * 2048 + qrow)) * 1024 + h * 64;
    bf16x8 qf0 = *reinterpret_cast<const bf16x8*>(qptr + g * 8);
    bf16x8 qf1 = *reinterpret_cast<const bf16x8*>(qptr + 32 + g * 8);

    float mrun = -INFINITY, lrun = 0.f;
    f32x4 o[4] = {};   // o[nt][e]: q = g*4+e, d = nt*16 + r

    int tr = t >> 3, tc = (t & 7) * 8;
    const size_t kvbase = (size_t)(b * 2048) * 1024 + h * 64;

    for (int kv = 0; kv < S; kv += 32) {
        bf16x8 kvec = *reinterpret_cast<const bf16x8*>(kg + kvbase + (size_t)(kv + tr) * 1024 + tc);
        bf16x8 vvec = *reinterpret_cast<const bf16x8*>(vg + kvbase + (size_t)(kv + tr) * 1024 + tc);
        __syncthreads();
        *reinterpret_cast<bf16x8*>(&Ks[tr][tc]) = kvec;
        #pragma unroll
        for (int j = 0; j < 8; ++j) Vs[tc + j][tr] = (unsigned short)vvec[j];
        __syncthreads();

        // QK^T (swapped): S^T[key][q]; lane holds S[q=r][key = kv + kt*16 + g*4 + e]
        f32x4 sc0 = {}, sc1 = {};
        {
            bf16x8 kf0 = *reinterpret_cast<const bf16x8*>(&Ks[r][g * 8]);
            bf16x8 kf1 = *reinterpret_cast<const bf16x8*>(&Ks[r][32 + g * 8]);
            sc0 = MFMA16x16x32(kf0, qf0, sc0);
            sc0 = MFMA16x16x32(kf1, qf1, sc0);
            bf16x8 kf2 = *reinterpret_cast<const bf16x8*>(&Ks[16 + r][g * 8]);
            bf16x8 kf3 = *reinterpret_cast<const bf16x8*>(&Ks[16 + r][32 + g * 8]);
            sc1 = MFMA16x16x32(kf2, qf0, sc1);
            sc1 = MFMA16x16x32(kf3, qf1, sc1);
        }

        float s8[8];
        float pmax = -INFINITY;
        #pragma unroll
        for (int kt = 0; kt < 2; ++kt) {
            #pragma unroll
            for (int e = 0; e < 4; ++e) {
                int key = kv + kt * 16 + g * 4 + e;
                int n = qrow - key; n = n > 0 ? n : 0;
                float val = (kt == 0 ? sc0[e] : sc1[e]) * 0.125f + bts[n];
                s8[kt * 4 + e] = val;
                pmax = fmaxf(pmax, val);
            }
        }
        pmax = fmaxf(pmax, __shfl_xor(pmax, 16));
        pmax = fmaxf(pmax, __shfl_xor(pmax, 32));
        float mnew = fmaxf(mrun, pmax);
        float scale = __expf(mrun - mnew);
        float rsum = 0.f;
        unsigned short pb[8];
        #pragma unroll
        for (int i = 0; i < 8; ++i) {
            float p = __expf(s8[i] - mnew);
            rsum += p;
            pb[i] = f2b(p);
        }
        rsum += __shfl_xor(rsum, 16);
        rsum += __shfl_xor(rsum, 32);
        lrun = lrun * scale + rsum;
        mrun = mnew;

        // write P tile (per-wave region; same-wave DS ops are in-order, no barrier needed)
        uint2 w0, w1;
        w0.x = (unsigned)pb[0] | ((unsigned)pb[1] << 16);
        w0.y = (unsigned)pb[2] | ((unsigned)pb[3] << 16);
        w1.x = (unsigned)pb[4] | ((unsigned)pb[5] << 16);
        w1.y = (unsigned)pb[6] | ((unsigned)pb[7] << 16);
        *reinterpret_cast<uint2*>(&Ps[w][r][g * 4]) = w0;
        *reinterpret_cast<uint2*>(&Ps[w][r][16 + g * 4]) = w1;

        // rescale O by exp(m_old - m_new), per accumulator row q = g*4+e
        float scl0 = __shfl(scale, g * 4 + 0);
        float scl1 = __shfl(scale, g * 4 + 1);
        float scl2 = __shfl(scale, g * 4 + 2);
        float scl3 = __shfl(scale, g * 4 + 3);
        #pragma unroll
        for (int nt = 0; nt < 4; ++nt) {
            o[nt][0] *= scl0; o[nt][1] *= scl1; o[nt][2] *= scl2; o[nt][3] *= scl3;
        }

        // PV: A = P [q][key], B = V^T [key][d]
        bf16x8 pf = *reinterpret_cast<const bf16x8*>(&Ps[w][r][g * 8]);
        #pragma unroll
        for (int nt = 0; nt < 4; ++nt) {
            bf16x8 vf = *reinterpret_cast<const bf16x8*>(&Vs[nt * 16 + r][g * 8]);
            o[nt] = MFMA16x16x32(pf, vf, o[nt]);
        }
    }

    float li0 = __shfl(lrun, g * 4 + 0);
    float li1 = __shfl(lrun, g * 4 + 1);
    float li2 = __shfl(lrun, g * 4 + 2);
    float li3 = __shfl(lrun, g * 4 + 3);
    #pragma unroll
    for (int e = 0; e < 4; ++e) {
        int qr = qt * 64 + w * 16 + g * 4 + e;
        float li = (e == 0) ? li0 : (e == 1) ? li1 : (e == 2) ? li2 : li3;
        size_t ob = ((size_t)(b * 2048 + qr)) * 1024 + h * 64 + r;
        #pragma unroll
        for (int nt = 0; nt < 4; ++nt)
            out[ob + nt * 16] = o[nt][e] / li;
    }
}

extern "C" void kernel_launch(void* const* d_in, const int* in_sizes, int n_in,
                              void* d_out, int out_size, void* d_ws, size_t ws_size,
                              hipStream_t stream) {
    const float* hidden = (const float*)d_in[0];
    const float* Wq = (const float*)d_in[1];
    const float* bq = (const float*)d_in[2];
    const float* Wk = (const float*)d_in[3];
    const float* bk = (const float*)d_in[4];
    const float* Wv = (const float*)d_in[5];
    const float* bv = (const float*)d_in[6];
    const float* rel_bias = (const float*)d_in[7];
    float* out = (float*)d_out;

    char* ws = (char*)d_ws;
    // workspace layout (bytes):
    //   hA bf16 [4096*1024]            @ 0         (8 MB)
    //   WT bf16 [3][1024*1024]         @ 8 MB      (6 MB)
    //   qkv bf16 [3][4096*1024]        @ 14 MB     (24 MB)
    //   bt fp32 [16*2048]              @ 38 MB     (128 KB)
    unsigned short* hA  = (unsigned short*)(ws);
    unsigned short* WT  = (unsigned short*)(ws + (size_t)8 * 1024 * 1024);
    unsigned short* qkv = (unsigned short*)(ws + (size_t)14 * 1024 * 1024);
    float* bt           = (float*)(ws + (size_t)38 * 1024 * 1024);

    cvt_bf16_kernel<<<4096, 256, 0, stream>>>(hidden, hA, 4096 * 1024);
    transpose_cvt_kernel<<<dim3(32, 32, 3), dim3(32, 8), 0, stream>>>(Wq, Wk, Wv, WT);
    build_bt_kernel<<<8, 256, 0, stream>>>(rel_bias, bt);
    gemm_qkv_kernel<<<dim3(32, 8, 3), 256, 0, stream>>>(hA, WT, bq, bk, bv, qkv);
    attn_kernel<<<dim3(32, 32), 256, 0, stream>>>(qkv, bt, out);
}